// Round 14
// baseline (22.999 us; speedup 1.0000x reference)
//
#include <hip/hip_runtime.h>
#include <math.h>

// BipolarMorphological2D SMorph as a bf16 MFMA GEMM (R14).
// delta-form: e^kf = 1 + delta -> d = S_m + GEMM(m,delta); n = S_mlm + GEMM(..)
//   M = 7200 (s*2+sign), N = 256 (o*4+tbl), K = 576 (c*2+{m,mlm} per 3x3 pos)
// R14 vs R13: (1) gemm = 900 x 1-wave blocks (launch_bounds(64,2): VGPR<=256,
// >=2 waves/SIMD resident, 3.5 blocks/CU dispatch balance) instead of 450x2
// (0.88 waves/SIMD). (2) prep A3-pack uses __logf (feeds bf16 pack, 8-bit
// mantissa target - hw log precision is ample); branch1 (fp32 sums) keeps logf.

typedef float  f32x4 __attribute__((ext_vector_type(4)));
typedef short  s16x8 __attribute__((ext_vector_type(8)));

#define BB   4
#define CC   32
#define HH   32
#define WW   32
#define OO   64
#define HO   30
#define WO   30
#define NSP  900
#define KDIM 576

#define T1   131072            // branch1: pixel sums
#define T2   (T1 + 518400)     // branch2: A3 pack
#define T3   (T2 + 18432)      // branch3: B pack

__device__ __forceinline__ unsigned short f2bf(float f) {
    unsigned u = __float_as_uint(f);
    return (unsigned short)((u + 0x7FFFu + ((u >> 16) & 1u)) >> 16);
}

// ---- prep: pixs[pix] = fp32 c-sums (Smp, Smlmp, Smn, Smlmn) per pixel
//            A3: bf16 A in MFMA-frag order: [mtile(225)][step(18)][mi(2)][lane(64)] x 16B
//            bt: bf16 B in MFMA-frag order: [ng(16)][step(18)][lane(64)] x 16B
__global__ __launch_bounds__(256) void smorph_prep(
    const float* __restrict__ x, const float* __restrict__ k1,
    const float* __restrict__ k2, float4* __restrict__ pixs,
    uint4* __restrict__ A3, unsigned short* __restrict__ bt)
{
    const int t = blockIdx.x * 256 + threadIdx.x;

    if (t < T1) {
        // t = pix*32 + c  (c innermost -> shfl reduction over c)
        const int pix = t >> 5, c = t & 31;
        const int b = pix >> 10, h = (pix >> 5) & 31, w = pix & 31;
        float v = x[b*32768 + c*1024 + h*32 + w];
        float mp = fmaxf(v, 0.1f), mn = fmaxf(-v, 0.1f);
        float lp = mp * logf(mp), ln_ = mn * logf(mn);
        float s0 = mp, s1 = lp, s2 = mn, s3 = ln_;
#pragma unroll
        for (int m = 16; m >= 1; m >>= 1) {
            s0 += __shfl_xor(s0, m); s1 += __shfl_xor(s1, m);
            s2 += __shfl_xor(s2, m); s3 += __shfl_xor(s3, m);
        }
        if (c == 0) pixs[pix] = make_float4(s0, s1, s2, s3);
    } else if (t < T2) {
        // A3 pack: u -> (mtile, step, mi, lane); 4 channels per thread
        const int u   = t - T1;
        const int mt  = u / 2304, rem = u - mt*2304;
        const int st  = rem >> 7, rem2 = rem & 127;
        const int mi  = rem2 >> 6, l = rem2 & 63;
        const int lr  = l & 15, lg = l >> 4;
        const int s   = mt*16 + mi*8 + (lr >> 1);
        const int sign = lr & 1;
        const int pos = st >> 1, khalf = st & 1;
        const int kh  = pos / 3, kw = pos - 3*(pos/3);
        const int b   = s / NSP, r = s - b*NSP;
        const int ho  = r / WO,  wo = r - WO*(r/WO);
        const int h   = ho + kh, w = wo + kw;
        const int c0  = khalf*16 + lg*4;
        const int base = b*32768 + h*32 + w;
        unsigned pk[4];
#pragma unroll
        for (int q = 0; q < 4; ++q) {
            float v = x[base + (c0 + q)*1024];
            float m = sign ? fmaxf(-v, 0.1f) : fmaxf(v, 0.1f);
            pk[q] = (unsigned)f2bf(m) | ((unsigned)f2bf(m * __logf(m)) << 16);
        }
        A3[u] = make_uint4(pk[0], pk[1], pk[2], pk[3]);
    } else if (t < T3) {
        // B pack: u -> (o, p); 4 tables x 2 k-slots
        const int u3 = t - T2;
        const int o = u3 & 63, p = u3 >> 6;
        const float a = k1[u3], b2 = k2[u3];
        const float d1 = expm1f(a),  q1 = a  * expf(a);
        const float d2 = expm1f(b2), q2 = b2 * expf(b2);
        const float vals[4][2] = {{d1, 0.f}, {q1, d1}, {d2, 0.f}, {q2, d2}};
#pragma unroll
        for (int tbl = 0; tbl < 4; ++tbl) {
            const int n = o*4 + tbl;
#pragma unroll
            for (int ks = 0; ks < 2; ++ks) {
                const int k    = 2*p + ks;
                const int st   = k >> 5, k32 = k & 31;
                const int lane = (n & 15) + ((k32 >> 3) << 4);
                bt[((n >> 4)*18 + st)*512 + lane*8 + (k32 & 7)] = f2bf(vals[tbl][ks]);
            }
        }
    }
}

// ---- GEMM + epilogue: 900 blocks x 64 thr (1 wave). Wave: 32M x 64N, K=576.
__global__ __launch_bounds__(64, 2) void smorph_gemm(
    const uint4* __restrict__ A3, const unsigned short* __restrict__ bt,
    const float4* __restrict__ pixs, const float* __restrict__ bias,
    float* __restrict__ out)
{
    __shared__ __align__(16) float lds[32*66];

    const int l   = threadIdx.x & 63;
    const int bm  = blockIdx.x >> 2;           // M-tile (16 s, 32 rows): 0..224
    const int nq  = blockIdx.x & 3;            // N-quarter
    const int N0  = nq*64;
    const int ng0 = nq*4;

    const int lr = l & 15;
    const int lg = l >> 4;

    // ---- per-lane fp32 window sums (issued first; used only in epilogue)
    float4 S;
    {
        const int s  = bm*16 + lr;
        const int b  = s / NSP, r = s - b*NSP;
        const int ho = r / WO,  wo = r - WO*(r/WO);
        const float4* P = pixs + (b*1024 + ho*32 + wo);
        float4 acc = make_float4(0,0,0,0);
#pragma unroll
        for (int kh = 0; kh < 3; ++kh)
#pragma unroll
            for (int kw = 0; kw < 3; ++kw) {
                float4 v = P[kh*32 + kw];
                acc.x += v.x; acc.y += v.y; acc.z += v.z; acc.w += v.w;
            }
        S = acc;
    }

    const uint4* Ap = A3 + ((size_t)bm*18)*128 + l;     // + (step*2+mi)*64
    const char*  pb = (const char*)bt;

    f32x4 acc[2][4] = {};

#pragma unroll
    for (int step = 0; step < 18; ++step) {
        s16x8 a0 = *(const s16x8*)(Ap + (step*2 + 0)*64);
        s16x8 a1 = *(const s16x8*)(Ap + (step*2 + 1)*64);
        s16x8 b0 = *(const s16x8*)(pb + (((ng0+0)*18 + step)*64 + l)*16);
        s16x8 b1 = *(const s16x8*)(pb + (((ng0+1)*18 + step)*64 + l)*16);
        s16x8 b2 = *(const s16x8*)(pb + (((ng0+2)*18 + step)*64 + l)*16);
        s16x8 b3 = *(const s16x8*)(pb + (((ng0+3)*18 + step)*64 + l)*16);

        acc[0][0] = __builtin_amdgcn_mfma_f32_16x16x32_bf16(a0, b0, acc[0][0], 0, 0, 0);
        acc[0][1] = __builtin_amdgcn_mfma_f32_16x16x32_bf16(a0, b1, acc[0][1], 0, 0, 0);
        acc[0][2] = __builtin_amdgcn_mfma_f32_16x16x32_bf16(a0, b2, acc[0][2], 0, 0, 0);
        acc[0][3] = __builtin_amdgcn_mfma_f32_16x16x32_bf16(a0, b3, acc[0][3], 0, 0, 0);
        acc[1][0] = __builtin_amdgcn_mfma_f32_16x16x32_bf16(a1, b0, acc[1][0], 0, 0, 0);
        acc[1][1] = __builtin_amdgcn_mfma_f32_16x16x32_bf16(a1, b1, acc[1][1], 0, 0, 0);
        acc[1][2] = __builtin_amdgcn_mfma_f32_16x16x32_bf16(a1, b2, acc[1][2], 0, 0, 0);
        acc[1][3] = __builtin_amdgcn_mfma_f32_16x16x32_bf16(a1, b3, acc[1][3], 0, 0, 0);
    }

    // ---- epilogue: acc -> LDS [row 0..31][col 0..63], pitch 66
    {
        const int wrbase = lg*4*66 + lr;
#pragma unroll
        for (int mi = 0; mi < 2; ++mi)
#pragma unroll
            for (int ni = 0; ni < 4; ++ni)
#pragma unroll
                for (int r = 0; r < 4; ++r)
                    lds[wrbase + (mi*16 + r)*66 + ni*16] = acc[mi][ni][r];
    }
    __syncthreads();

    {
        const int sl = lr;                      // local s (S already per-lane)
        const int oq = lg;                      // o-quarter
        const int s  = bm*16 + sl;
        const int b  = s / NSP;
        const int r900 = s - b*NSP;
#pragma unroll
        for (int oi = 0; oi < 4; ++oi) {
            int ol = oq*4 + oi;
            int o  = (N0 >> 2) + ol;
            float4 v0 = *(const float4*)&lds[(2*sl + 0)*66 + ol*4];  // pos: d1,n1,d2,n2
            float4 v1 = *(const float4*)&lds[(2*sl + 1)*66 + ol*4];  // neg
            float d1p = S.x + v0.x, n1p = S.y + v0.y;
            float d2p = S.x + v0.z, n2p = S.y + v0.w;
            float d1n = S.z + v1.x, n1n = S.w + v1.y;
            float d2n = S.z + v1.z, n2n = S.w + v1.w;
            float P = __expf(n1p/d1p) - __expf(n2p/d2p)
                    - __expf(n1n/d1n) + __expf(n2n/d2n);
            out[((size_t)(b*OO + o))*NSP + r900] = P + bias[o];
        }
    }
}

extern "C" void kernel_launch(void* const* d_in, const int* in_sizes, int n_in,
                              void* d_out, int out_size, void* d_ws, size_t ws_size,
                              hipStream_t stream) {
    const float* x    = (const float*)d_in[0];
    const float* k1   = (const float*)d_in[1];
    const float* k2   = (const float*)d_in[2];
    const float* bias = (const float*)d_in[3];

    char* ws = (char*)d_ws;
    float4*         pixs = (float4*)(ws);                 // 64 KB
    uint4*          A3   = (uint4*)(ws + 0x10000);        // 8,294,400 B
    unsigned short* bt   = (unsigned short*)(ws + 0x7F9000); // 294,912 B
    float*          out  = (float*)d_out;

    hipLaunchKernelGGL(smorph_prep, dim3((T3 + 255)/256), dim3(256), 0, stream,
                       x, k1, k2, pixs, A3, bt);
    hipLaunchKernelGGL(smorph_gemm, dim3(900), dim3(64), 0, stream,
                       A3, bt, pixs, bias, out);
}

// Round 15
// 20.778 us; speedup vs baseline: 1.1069x; 1.1069x over previous
//
#include <hip/hip_runtime.h>
#include <math.h>

// BipolarMorphological2D SMorph as a bf16 MFMA GEMM (R15).
// delta-form: e^kf = 1 + delta -> d = S_m + GEMM(m,delta); n = S_mlm + GEMM(..)
//   M = 7200 (s*2+sign), N = 256 (o*4+tbl), K = 576 (c*2+{m,mlm} per 3x3 pos)
// R15 vs R13: gemm K-split-2 in-block. 450 blocks x 4 waves (kq = K-half by
// step parity, nhf = N-half): each wave runs 9 of 18 steps (half the serial
// L2/L3-load chain), 1800 waves = 1.76/SIMD with 2 waves/SIMD co-resident
// (launch_bounds(256,2)). kq1 dumps 32 acc f32/lane to LDS (r-major,
// conflict-free), kq0 adds + runs the proven epilogue. Prep unchanged (R14).

typedef float  f32x4 __attribute__((ext_vector_type(4)));
typedef short  s16x8 __attribute__((ext_vector_type(8)));

#define BB   4
#define CC   32
#define HH   32
#define WW   32
#define OO   64
#define HO   30
#define WO   30
#define NSP  900
#define KDIM 576

#define T1   131072            // branch1: pixel sums
#define T2   (T1 + 518400)     // branch2: A3 pack
#define T3   (T2 + 18432)      // branch3: B pack

__device__ __forceinline__ unsigned short f2bf(float f) {
    unsigned u = __float_as_uint(f);
    return (unsigned short)((u + 0x7FFFu + ((u >> 16) & 1u)) >> 16);
}

// ---- prep: pixs[pix] = fp32 c-sums (Smp, Smlmp, Smn, Smlmn) per pixel
//            A3: bf16 A in MFMA-frag order: [mtile(225)][step(18)][mi(2)][lane(64)] x 16B
//            bt: bf16 B in MFMA-frag order: [ng(16)][step(18)][lane(64)] x 16B
__global__ __launch_bounds__(256) void smorph_prep(
    const float* __restrict__ x, const float* __restrict__ k1,
    const float* __restrict__ k2, float4* __restrict__ pixs,
    uint4* __restrict__ A3, unsigned short* __restrict__ bt)
{
    const int t = blockIdx.x * 256 + threadIdx.x;

    if (t < T1) {
        const int pix = t >> 5, c = t & 31;
        const int b = pix >> 10, h = (pix >> 5) & 31, w = pix & 31;
        float v = x[b*32768 + c*1024 + h*32 + w];
        float mp = fmaxf(v, 0.1f), mn = fmaxf(-v, 0.1f);
        float lp = mp * logf(mp), ln_ = mn * logf(mn);
        float s0 = mp, s1 = lp, s2 = mn, s3 = ln_;
#pragma unroll
        for (int m = 16; m >= 1; m >>= 1) {
            s0 += __shfl_xor(s0, m); s1 += __shfl_xor(s1, m);
            s2 += __shfl_xor(s2, m); s3 += __shfl_xor(s3, m);
        }
        if (c == 0) pixs[pix] = make_float4(s0, s1, s2, s3);
    } else if (t < T2) {
        const int u   = t - T1;
        const int mt  = u / 2304, rem = u - mt*2304;
        const int st  = rem >> 7, rem2 = rem & 127;
        const int mi  = rem2 >> 6, l = rem2 & 63;
        const int lr  = l & 15, lg = l >> 4;
        const int s   = mt*16 + mi*8 + (lr >> 1);
        const int sign = lr & 1;
        const int pos = st >> 1, khalf = st & 1;
        const int kh  = pos / 3, kw = pos - 3*(pos/3);
        const int b   = s / NSP, r = s - b*NSP;
        const int ho  = r / WO,  wo = r - WO*(r/WO);
        const int h   = ho + kh, w = wo + kw;
        const int c0  = khalf*16 + lg*4;
        const int base = b*32768 + h*32 + w;
        unsigned pk[4];
#pragma unroll
        for (int q = 0; q < 4; ++q) {
            float v = x[base + (c0 + q)*1024];
            float m = sign ? fmaxf(-v, 0.1f) : fmaxf(v, 0.1f);
            pk[q] = (unsigned)f2bf(m) | ((unsigned)f2bf(m * __logf(m)) << 16);
        }
        A3[u] = make_uint4(pk[0], pk[1], pk[2], pk[3]);
    } else if (t < T3) {
        const int u3 = t - T2;
        const int o = u3 & 63, p = u3 >> 6;
        const float a = k1[u3], b2 = k2[u3];
        const float d1 = expm1f(a),  q1 = a  * expf(a);
        const float d2 = expm1f(b2), q2 = b2 * expf(b2);
        const float vals[4][2] = {{d1, 0.f}, {q1, d1}, {d2, 0.f}, {q2, d2}};
#pragma unroll
        for (int tbl = 0; tbl < 4; ++tbl) {
            const int n = o*4 + tbl;
#pragma unroll
            for (int ks = 0; ks < 2; ++ks) {
                const int k    = 2*p + ks;
                const int st   = k >> 5, k32 = k & 31;
                const int lane = (n & 15) + ((k32 >> 3) << 4);
                bt[((n >> 4)*18 + st)*512 + lane*8 + (k32 & 7)] = f2bf(vals[tbl][ks]);
            }
        }
    }
}

// ---- GEMM: 450 blocks x 256 thr (4 waves: kq x nhf). Wave: 32M x 64N x 9 steps.
__global__ __launch_bounds__(256, 2) void smorph_gemm(
    const uint4* __restrict__ A3, const unsigned short* __restrict__ bt,
    const float4* __restrict__ pixs, const float* __restrict__ bias,
    float* __restrict__ out)
{
    __shared__ float cmb[2][2048];               // 16 KB: K-combine, r-major
    __shared__ __align__(16) float epi[2][32*66];// 16.9 KB: epilogue transpose

    const int tid = threadIdx.x;
    const int l   = tid & 63;
    const int w   = tid >> 6;                  // wave 0..3
    const int kq  = w >> 1;                    // K-half (step parity)
    const int nhf = w & 1;                     // N-half within block
    const int bm  = blockIdx.x >> 1;           // M-tile (16 s, 32 rows)
    const int nh  = blockIdx.x & 1;
    const int N0  = nh*128 + nhf*64;
    const int ng0 = N0 >> 4;

    const int lr = l & 15;
    const int lg = l >> 4;

    // ---- per-lane fp32 window sums (epilogue only)
    float4 S;
    {
        const int s  = bm*16 + lr;
        const int b  = s / NSP, r = s - b*NSP;
        const int ho = r / WO,  wo = r - WO*(r/WO);
        const float4* P = pixs + (b*1024 + ho*32 + wo);
        float4 a = make_float4(0,0,0,0);
#pragma unroll
        for (int kh = 0; kh < 3; ++kh)
#pragma unroll
            for (int kw = 0; kw < 3; ++kw) {
                float4 v = P[kh*32 + kw];
                a.x += v.x; a.y += v.y; a.z += v.z; a.w += v.w;
            }
        S = a;
    }

    const uint4* Ap = A3 + ((size_t)bm*18)*128 + l;
    const char*  pb = (const char*)bt;

    f32x4 acc[2][4] = {};

#pragma unroll
    for (int s2 = 0; s2 < 9; ++s2) {
        const int step = s2*2 + kq;            // this wave's 9 steps
        s16x8 a0 = *(const s16x8*)(Ap + (step*2 + 0)*64);
        s16x8 a1 = *(const s16x8*)(Ap + (step*2 + 1)*64);
        s16x8 b0 = *(const s16x8*)(pb + (((ng0+0)*18 + step)*64 + l)*16);
        s16x8 b1 = *(const s16x8*)(pb + (((ng0+1)*18 + step)*64 + l)*16);
        s16x8 b2 = *(const s16x8*)(pb + (((ng0+2)*18 + step)*64 + l)*16);
        s16x8 b3 = *(const s16x8*)(pb + (((ng0+3)*18 + step)*64 + l)*16);

        acc[0][0] = __builtin_amdgcn_mfma_f32_16x16x32_bf16(a0, b0, acc[0][0], 0, 0, 0);
        acc[0][1] = __builtin_amdgcn_mfma_f32_16x16x32_bf16(a0, b1, acc[0][1], 0, 0, 0);
        acc[0][2] = __builtin_amdgcn_mfma_f32_16x16x32_bf16(a0, b2, acc[0][2], 0, 0, 0);
        acc[0][3] = __builtin_amdgcn_mfma_f32_16x16x32_bf16(a0, b3, acc[0][3], 0, 0, 0);
        acc[1][0] = __builtin_amdgcn_mfma_f32_16x16x32_bf16(a1, b0, acc[1][0], 0, 0, 0);
        acc[1][1] = __builtin_amdgcn_mfma_f32_16x16x32_bf16(a1, b1, acc[1][1], 0, 0, 0);
        acc[1][2] = __builtin_amdgcn_mfma_f32_16x16x32_bf16(a1, b2, acc[1][2], 0, 0, 0);
        acc[1][3] = __builtin_amdgcn_mfma_f32_16x16x32_bf16(a1, b3, acc[1][3], 0, 0, 0);
    }

    // ---- K-combine: kq1 -> LDS (r-major, conflict-free), kq0 adds
    if (kq == 1) {
#pragma unroll
        for (int mi = 0; mi < 2; ++mi)
#pragma unroll
            for (int ni = 0; ni < 4; ++ni)
#pragma unroll
                for (int r = 0; r < 4; ++r)
                    cmb[nhf][(mi*16 + ni*4 + r)*64 + l] = acc[mi][ni][r];
    }
    __syncthreads();
    if (kq == 0) {
#pragma unroll
        for (int mi = 0; mi < 2; ++mi)
#pragma unroll
            for (int ni = 0; ni < 4; ++ni)
#pragma unroll
                for (int r = 0; r < 4; ++r)
                    acc[mi][ni][r] += cmb[nhf][(mi*16 + ni*4 + r)*64 + l];

        // epilogue write: acc -> epi[nhf] [row 0..31][col 0..63], pitch 66
        const int wrbase = lg*4*66 + lr;
#pragma unroll
        for (int mi = 0; mi < 2; ++mi)
#pragma unroll
            for (int ni = 0; ni < 4; ++ni)
#pragma unroll
                for (int r = 0; r < 4; ++r)
                    epi[nhf][wrbase + (mi*16 + r)*66 + ni*16] = acc[mi][ni][r];
    }
    __syncthreads();

    if (kq == 0) {
        const int sl = lr;
        const int oq = lg;
        const int s  = bm*16 + sl;
        const int b  = s / NSP;
        const int r900 = s - b*NSP;
#pragma unroll
        for (int oi = 0; oi < 4; ++oi) {
            int ol = oq*4 + oi;
            int o  = (N0 >> 2) + ol;
            float4 v0 = *(const float4*)&epi[nhf][(2*sl + 0)*66 + ol*4];  // pos
            float4 v1 = *(const float4*)&epi[nhf][(2*sl + 1)*66 + ol*4];  // neg
            float d1p = S.x + v0.x, n1p = S.y + v0.y;
            float d2p = S.x + v0.z, n2p = S.y + v0.w;
            float d1n = S.z + v1.x, n1n = S.w + v1.y;
            float d2n = S.z + v1.z, n2n = S.w + v1.w;
            float P = __expf(n1p/d1p) - __expf(n2p/d2p)
                    - __expf(n1n/d1n) + __expf(n2n/d2n);
            out[((size_t)(b*OO + o))*NSP + r900] = P + bias[o];
        }
    }
}

extern "C" void kernel_launch(void* const* d_in, const int* in_sizes, int n_in,
                              void* d_out, int out_size, void* d_ws, size_t ws_size,
                              hipStream_t stream) {
    const float* x    = (const float*)d_in[0];
    const float* k1   = (const float*)d_in[1];
    const float* k2   = (const float*)d_in[2];
    const float* bias = (const float*)d_in[3];

    char* ws = (char*)d_ws;
    float4*         pixs = (float4*)(ws);                 // 64 KB
    uint4*          A3   = (uint4*)(ws + 0x10000);        // 8,294,400 B
    unsigned short* bt   = (unsigned short*)(ws + 0x7F9000); // 294,912 B
    float*          out  = (float*)d_out;

    hipLaunchKernelGGL(smorph_prep, dim3((T3 + 255)/256), dim3(256), 0, stream,
                       x, k1, k2, pixs, A3, bt);
    hipLaunchKernelGGL(smorph_gemm, dim3(450), dim3(256), 0, stream,
                       A3, bt, pixs, bias, out);
}